// Round 4
// baseline (2196.423 us; speedup 1.0000x reference)
//
#include <hip/hip_runtime.h>

#define NXY 160
#define NT 12
#define SP 25600                  // 160*160
#define SPH ((size_t)SP*128)      // u16 per [hi] or [lo] slab

typedef unsigned short u16;
typedef unsigned int u32;
typedef float f32x4 __attribute__((ext_vector_type(4)));
typedef __bf16 bf16x8 __attribute__((ext_vector_type(8)));

__device__ __forceinline__ int refl(int p){ return p<0 ? -p : (p>=NXY ? 2*(NXY-1)-p : p); }
__device__ __forceinline__ u16 bf16_rn(float x){
    u32 u = __float_as_uint(x);
    return (u16)((u + 0x7fffu + ((u>>16)&1u)) >> 16);
}
__device__ __forceinline__ float bf16_f(u16 h){ return __uint_as_float(((u32)h)<<16); }
__device__ __forceinline__ bf16x8 as_bf(uint4 v){ return __builtin_bit_cast(bf16x8, v); }

// ---------------- pack weights: per chunk c (16KB): [hi 4096 u16 | lo 4096 u16] -----------------
// chunk c = tap*4+icb ; within: fragment (slot,m,j): u16 idx (slot*128+m)*8+j
// k = slot*8+j -> ic = icb*16 + slot*4 + (j>>1), ri = j&1
// m<64 (real out): ri0 -> wr, ri1 -> -wi ; m>=64 (imag out): ri0 -> wi, ri1 -> wr
__global__ void pack_w_kernel(const float* __restrict__ wr, const float* __restrict__ wi,
                              u16* __restrict__ Ap)
{
    const int c = blockIdx.x, m = threadIdx.x;
    const int tap = c>>2, icb = c&3;
    const int oc = m & 63; const bool imr = m >= 64;
    for (int slot=0; slot<4; ++slot)
        for (int j=0; j<8; ++j){
            int ic = icb*16 + slot*4 + (j>>1);
            int ri = j&1;
            float vr = wr[(oc*64+ic)*9+tap], vi = wi[(oc*64+ic)*9+tap];
            float val = imr ? (ri ? vr : vi) : (ri ? -vi : vr);
            u16 h = bf16_rn(val);
            int fi = (slot*128+m)*8 + j;
            Ap[c*8192 + fi]        = h;
            Ap[c*8192 + 4096 + fi] = bf16_rn(val - bf16_f(h));
        }
}

// ---------------- pack iter (2 time steps per launch) into pixel-major bf16 hi/lo ---------------
__global__ __launch_bounds__(256) void pack_iter_kernel(const float* __restrict__ it_r,
        const float* __restrict__ it_i, u16* __restrict__ H, int t0)
{
    __shared__ u32 smem[16384];
    const int t = t0 + blockIdx.y;
    u16* dst = H + (size_t)blockIdx.y * 2 * SPH;
    const int px0 = blockIdx.x * 128;
    const int tid = threadIdx.x;
    const int pxl = tid & 127, half = tid >> 7;
    const int px = px0 + pxl;
    for (int i=0; i<32; ++i){
        int ic = i*2 + half;
        float r  = it_r[((size_t)ic*NT + t)*SP + px];
        float im = it_i[((size_t)ic*NT + t)*SP + px];
        u16 rh = bf16_rn(r), ih = bf16_rn(im);
        u16 rl = bf16_rn(r - bf16_f(rh)), il = bf16_rn(im - bf16_f(ih));
        int dw = pxl*64 + (ic ^ (pxl&31));
        smem[dw]        = (u32)rh | ((u32)ih<<16);
        smem[8192 + dw] = (u32)rl | ((u32)il<<16);
    }
    __syncthreads();
    uint4* gh = (uint4*)dst;
    uint4* gl = (uint4*)(dst + SPH);
    for (int i=0; i<8; ++i){
        int pxr = i*16 + (tid>>4);
        int q = tid & 15;
        uint4 v, v2;
        #pragma unroll
        for (int d=0; d<4; ++d){
            ((u32*)&v )[d] = smem[        pxr*64 + ((q*4+d) ^ (pxr&31))];
            ((u32*)&v2)[d] = smem[8192 + pxr*64 + ((q*4+d) ^ (pxr&31))];
        }
        gh[(size_t)(px0+pxr)*16 + q] = v;
        gl[(size_t)(px0+pxr)*16 + q] = v2;
    }
}

// ---------------- i2h: 2-channel input conv + ALL biases -> pre (float2 [t][64][SP]) -------------
__global__ __launch_bounds__(256) void i2h_kernel(
    const float* __restrict__ in_r, const float* __restrict__ in_i,
    const float* __restrict__ w2r,  const float* __restrict__ w2i,
    const float* __restrict__ b2r,  const float* __restrict__ b2i,
    const float* __restrict__ bihr, const float* __restrict__ bihi,
    const float* __restrict__ bhhr, const float* __restrict__ bhhi,
    float2* __restrict__ pre)
{
    const int t = blockIdx.z, oc0 = blockIdx.y*8;
    const int px = blockIdx.x*256 + threadIdx.x;
    const int x = px/NXY, y = px - x*NXY;
    int offs[9];
    #pragma unroll
    for (int dx=-1; dx<=1; ++dx)
        #pragma unroll
        for (int dy=-1; dy<=1; ++dy)
            offs[(dx+1)*3+(dy+1)] = refl(x+dx)*NXY + refl(y+dy);
    float xr[2][9], xi[2][9];
    #pragma unroll
    for (int ic=0; ic<2; ++ic)
        #pragma unroll
        for (int k=0; k<9; ++k){
            xr[ic][k] = in_r[((size_t)ic*NT+t)*SP + offs[k]];
            xi[ic][k] = in_i[((size_t)ic*NT+t)*SP + offs[k]];
        }
    #pragma unroll
    for (int o=0; o<8; ++o){
        int oc = oc0+o;
        float ar = b2r[oc]+bihr[oc]+bhhr[oc];
        float ai = b2i[oc]+bihi[oc]+bhhi[oc];
        #pragma unroll
        for (int ic=0; ic<2; ++ic)
            #pragma unroll
            for (int k=0; k<9; ++k){
                float wr = w2r[(oc*2+ic)*9+k], wi = w2i[(oc*2+ic)*9+k];
                ar = fmaf(xr[ic][k], wr, ar); ar = fmaf(-xi[ic][k], wi, ar);
                ai = fmaf(xr[ic][k], wi, ai); ai = fmaf( xi[ic][k], wr, ai);
            }
        pre[((size_t)t*64+oc)*SP + px] = make_float2(ar, ai);
    }
}

// ---------------- the GEMM: MODE 0 = precompute (pre += W_ih * iter), MODE 1 = recurrence step --
// Block: 4 waves x 256 threads; block tile = M128 x 256px; wave tile = M128 x 64px (nt=4).
// A chunk (k=32, 16KB hi+lo) double-buffered in LDS via global_load_lds; B double-buffered in regs.
template<int MODE>
__global__ __launch_bounds__(256, 1) void gemm_kernel(
    const u16* __restrict__ Apk,   // [36 chunks][hi 4096 | lo 4096] u16
    const u16* __restrict__ Bpit,  // MODE0: pit base (y-indexed); MODE1 unused
    float2* __restrict__ pre,      // MODE0: base for t0 (y adds); MODE1: full base
    float2* __restrict__ out,
    const float* __restrict__ modb,
    u16* __restrict__ H,
    int s)
{
    __shared__ u32 smem[8192];     // 32KB: 2 x 16KB A-chunk buffers
    const int tid = threadIdx.x;
    const int lane = tid & 63, w = tid >> 6;
    const int l15 = lane & 15, l4 = lane >> 4;

    const u16* Bh; float2* pre_t;
    int dir = 0, t = 0;
    if constexpr (MODE==0){
        Bh = Bpit + (size_t)blockIdx.y*2*SPH;
        pre_t = pre + (size_t)blockIdx.y*64*SP;
    } else {
        dir = blockIdx.y;
        int rp = (s+1)&1;
        Bh = H + (size_t)(dir*2+rp)*2*SPH;
        t = dir ? (NT-1-s) : s;
        pre_t = pre + (size_t)t*64*SP;
    }
    const uint4* Bh4 = (const uint4*)Bh;
    const uint4* Bl4 = (const uint4*)(Bh + SPH);

    const int px0 = blockIdx.x*256;
    const int wpx0 = px0 + w*64;

    f32x4 acc[8][4];
    #pragma unroll
    for (int mt=0; mt<8; ++mt)
        #pragma unroll
        for (int nt=0; nt<4; ++nt) acc[mt][nt] = 0.f;

    const bool hasK = (MODE==0) || (s>0);
    if (hasK){
        int xn[4], yn[4];
        #pragma unroll
        for (int nt=0; nt<4; ++nt){
            int px = wpx0 + nt*16 + l15;
            xn[nt] = px/NXY; yn[nt] = px - xn[nt]*NXY;
        }
        const char* Ab = (const char*)Apk;

        auto stageA = [&](int cc, int par){
            const char* g = Ab + (size_t)cc*16384 + w*4096 + lane*16;
            char* l = ((char*)smem) + par*16384 + w*4096;
            #pragma unroll
            for (int i=0; i<4; ++i)
                __builtin_amdgcn_global_load_lds(
                    (const __attribute__((address_space(1))) u32*)(g + i*1024),
                    (__attribute__((address_space(3))) u32*)(l + i*1024), 16, 0, 0);
        };
        auto loadB = [&](uint4 (&d)[8], const int* po, int icb){
            #pragma unroll
            for (int nt=0; nt<4; ++nt){
                size_t o = (size_t)po[nt]*16 + icb*4 + l4;
                d[nt]   = Bh4[o];
                d[4+nt] = Bl4[o];
            }
        };
        auto compute = [&](const uint4 (&bb)[8], int par){
            const uint4* s4 = ((const uint4*)smem) + (par ? 1024 : 0);
            bf16x8 bhf[4], blf[4];
            #pragma unroll
            for (int nt=0; nt<4; ++nt){ bhf[nt]=as_bf(bb[nt]); blf[nt]=as_bf(bb[4+nt]); }
            #pragma unroll
            for (int mt=0; mt<8; ++mt){
                bf16x8 ah = as_bf(s4[      l4*128 + mt*16 + l15]);
                bf16x8 al = as_bf(s4[512 + l4*128 + mt*16 + l15]);
                #pragma unroll
                for (int nt=0; nt<4; ++nt){
                    acc[mt][nt] = __builtin_amdgcn_mfma_f32_16x16x32_bf16(ah, bhf[nt], acc[mt][nt], 0,0,0);
                    acc[mt][nt] = __builtin_amdgcn_mfma_f32_16x16x32_bf16(ah, blf[nt], acc[mt][nt], 0,0,0);
                    acc[mt][nt] = __builtin_amdgcn_mfma_f32_16x16x32_bf16(al, bhf[nt], acc[mt][nt], 0,0,0);
                }
            }
        };

        int poA[4], poB[4];
        #pragma unroll
        for (int nt=0; nt<4; ++nt) poA[nt] = refl(xn[nt]-1)*NXY + refl(yn[nt]-1);
        uint4 b0[8], b1[8];
        loadB(b0, poA, 0);
        stageA(0, 0);
        __syncthreads();

        for (int tap=0; tap<9; ++tap){
            if (tap < 8){
                int dx = (tap+1)/3 - 1, dy = (tap+1)%3 - 1;
                #pragma unroll
                for (int nt=0; nt<4; ++nt) poB[nt] = refl(xn[nt]+dx)*NXY + refl(yn[nt]+dy);
            }
            const int cb = tap*4;
            loadB(b1, poA, 1); stageA(cb+1, 1); compute(b0, 0); __syncthreads();
            loadB(b0, poA, 2); stageA(cb+2, 0); compute(b1, 1); __syncthreads();
            loadB(b1, poA, 3); stageA(cb+3, 1); compute(b0, 0); __syncthreads();
            if (tap < 8){ loadB(b0, poB, 0); stageA(cb+4, 0); }
            compute(b1, 1); __syncthreads();
            #pragma unroll
            for (int nt=0; nt<4; ++nt) poA[nt] = poB[nt];
        }
    }

    if constexpr (MODE==0){
        #pragma unroll
        for (int mt=0; mt<4; ++mt)
            #pragma unroll
            for (int nt=0; nt<4; ++nt){
                int px = wpx0 + nt*16 + l15;
                #pragma unroll
                for (int r=0; r<4; ++r){
                    int oc = mt*16 + l4*4 + r;
                    float2 p = pre_t[(size_t)oc*SP + px];
                    p.x += acc[mt][nt][r];
                    p.y += acc[mt+4][nt][r];
                    pre_t[(size_t)oc*SP + px] = p;
                }
            }
    } else {
        const int wp = s&1;
        u16* Ch = H + (size_t)(dir*2+wp)*2*SPH;
        uint4* Ch4 = (uint4*)Ch;
        uint4* Cl4 = (uint4*)(Ch + SPH);
        const bool first = (s<=5);
        #pragma unroll
        for (int mt=0; mt<4; ++mt)
            #pragma unroll
            for (int nt=0; nt<4; ++nt){
                int px = wpx0 + nt*16 + l15;
                uint4 hv, lv;
                #pragma unroll
                for (int r=0; r<4; ++r){
                    int oc = mt*16 + l4*4 + r;
                    float2 p = pre_t[(size_t)oc*SP + px];
                    float zr = p.x + acc[mt][nt][r];
                    float zi = p.y + acc[mt+4][nt][r];
                    float mag = sqrtf(zr*zr + zi*zi);
                    float sc = fmaxf(mag + modb[oc], 0.f) / (mag + 1e-8f);
                    float hr = sc*zr, hm = sc*zi;
                    size_t oidx = ((size_t)oc*NT + t)*SP + px;
                    if (first) out[oidx] = make_float2(hr, hm);
                    else { float2 o2 = out[oidx]; out[oidx] = make_float2(o2.x+hr, o2.y+hm); }
                    u16 rh = bf16_rn(hr), ih = bf16_rn(hm);
                    u16 rl = bf16_rn(hr - bf16_f(rh)), il = bf16_rn(hm - bf16_f(ih));
                    ((u32*)&hv)[r] = (u32)rh | ((u32)ih<<16);
                    ((u32*)&lv)[r] = (u32)rl | ((u32)il<<16);
                }
                size_t q = (size_t)px*16 + mt*4 + l4;
                Ch4[q] = hv; Cl4[q] = lv;
            }
    }
}

extern "C" void kernel_launch(void* const* d_in, const int* in_sizes, int n_in,
                              void* d_out, int out_size, void* d_ws, size_t ws_size,
                              hipStream_t stream)
{
    const float* in_r  = (const float*)d_in[0];
    const float* in_i  = (const float*)d_in[1];
    const float* it_r  = (const float*)d_in[2];
    const float* it_i  = (const float*)d_in[3];
    const float* w2_r  = (const float*)d_in[4];
    const float* w2_i  = (const float*)d_in[5];
    const float* b2_r  = (const float*)d_in[6];
    const float* b2_i  = (const float*)d_in[7];
    const float* whh_r = (const float*)d_in[8];
    const float* whh_i = (const float*)d_in[9];
    const float* bhh_r = (const float*)d_in[10];
    const float* bhh_i = (const float*)d_in[11];
    const float* wih_r = (const float*)d_in[12];
    const float* wih_i = (const float*)d_in[13];
    const float* bih_r = (const float*)d_in[14];
    const float* bih_i = (const float*)d_in[15];
    const float* mod_b = (const float*)d_in[16];

    char* ws = (char*)d_ws;
    float2* pre = (float2*)ws;                                   // 157,286,400 B
    u16*    H   = (u16*)(ws + 157286400);                        //  52,428,800 B
    u16*    Ahh = (u16*)(ws + 157286400 + 52428800);             //     589,824 B
    u16*    Aih = H + 4*SPH;                                     // overlaps dir-1 h (dead in MODE0 phase)
    float2* out = (float2*)d_out;

    pack_w_kernel<<<36, 128, 0, stream>>>(whh_r, whh_i, Ahh);
    pack_w_kernel<<<36, 128, 0, stream>>>(wih_r, wih_i, Aih);
    i2h_kernel<<<dim3(100,8,12), 256, 0, stream>>>(in_r, in_i, w2_r, w2_i,
        b2_r, b2_i, bih_r, bih_i, bhh_r, bhh_i, pre);
    for (int t0=0; t0<NT; t0+=2){
        pack_iter_kernel<<<dim3(200,2), 256, 0, stream>>>(it_r, it_i, H, t0);
        gemm_kernel<0><<<dim3(100,2), 256, 0, stream>>>(Aih, H, pre + (size_t)t0*64*SP,
            nullptr, nullptr, nullptr, 0);
    }
    for (int s=0; s<NT; ++s)
        gemm_kernel<1><<<dim3(100,2), 256, 0, stream>>>(Ahh, nullptr, pre,
            out, mod_b, H, s);
}

// Round 5
// 1814.237 us; speedup vs baseline: 1.2107x; 1.2107x over previous
//
#include <hip/hip_runtime.h>

#define NXY 160
#define NT 12
#define SP 25600
#define SLAB_U16 3276800ull          // one hi or lo slab: 8*SP*16 u16
#define SLOT_U16 6553600ull          // hi+lo pair
#define SLAB_U4  409600              // SLAB_U16/8 (uint4 units)

typedef unsigned short u16;
typedef unsigned int u32;
typedef float f32x16 __attribute__((ext_vector_type(16)));
typedef __bf16 bf16x8 __attribute__((ext_vector_type(8)));

__device__ __forceinline__ int refl(int p){ return p<0 ? -p : (p>=NXY ? 2*(NXY-1)-p : p); }
__device__ __forceinline__ u16 bf16_rn(float x){
    u32 u = __float_as_uint(x);
    return (u16)((u + 0x7fffu + ((u>>16)&1u)) >> 16);
}
__device__ __forceinline__ float bf16_f(u16 h){ return __uint_as_float(((u32)h)<<16); }
__device__ __forceinline__ bf16x8 as_bf(uint4 v){ return __builtin_bit_cast(bf16x8, v); }

// ---- pack weights for 32x32x16 MFMA A-frags: [c16 = tap*8+sub][hl][MT][lane][8 u16] -------------
// M-row m = MT*32+row: oc = MT*16 + (row&15), ri_out = row>>4 (real/imag rows interleaved per tile)
// k within sub: k = (lane>>5)*8 + j -> ic = sub*8 + (lane>>5)*4 + (j>>1), ri = j&1
__global__ void pack_w_kernel(const float* __restrict__ wr, const float* __restrict__ wi,
                              u16* __restrict__ Ap)
{
    const int c16 = blockIdx.x;           // 0..71
    const int tap = c16>>3, sub = c16&7;
    const int t = threadIdx.x;
    const int lane = t & 63, MT = t >> 6;
    const int row = lane & 31;
    const int oc = MT*16 + (row & 15);
    const int ri_out = row >> 4;
    const int kh = lane >> 5;
    #pragma unroll
    for (int j = 0; j < 8; ++j){
        int ic = sub*8 + kh*4 + (j>>1);
        int ri = j & 1;
        float wrv = wr[(oc*64+ic)*9 + tap];
        float wiv = wi[(oc*64+ic)*9 + tap];
        float val = (ri_out==0) ? (ri ? -wiv : wrv) : (ri ? wrv : wiv);
        u16 h = bf16_rn(val);
        Ap[(size_t)(((c16*2+0)*4 + MT)*512 + lane*8 + j)] = h;
        Ap[(size_t)(((c16*2+1)*4 + MT)*512 + lane*8 + j)] = bf16_rn(val - bf16_f(h));
    }
}

// ---- pack iter into B-slab layout: [icb 8][px][16 u16] hi-slab + lo-slab, 2 t per launch --------
__global__ __launch_bounds__(256) void pack_iter_kernel(const float* __restrict__ it_r,
        const float* __restrict__ it_i, u16* __restrict__ H, int t0)
{
    __shared__ u32 smh[8192], sml[8192];      // 128 px x 64 ch-words each (32KB+32KB)
    const int t = t0 + blockIdx.y;
    const int tid = threadIdx.x;
    const int pxl = tid & 127, half = tid >> 7;
    const int px0 = blockIdx.x * 128;
    const int px = px0 + pxl;
    #pragma unroll 4
    for (int i = 0; i < 32; ++i){
        int ic = half*32 + i;
        float r  = it_r[((size_t)ic*NT + t)*SP + px];
        float im = it_i[((size_t)ic*NT + t)*SP + px];
        u16 rh = bf16_rn(r),  ih = bf16_rn(im);
        u16 rl = bf16_rn(r - bf16_f(rh)), il = bf16_rn(im - bf16_f(ih));
        int wofs = pxl*64 + (ic ^ (pxl & 31));
        smh[wofs] = (u32)rh | ((u32)ih << 16);
        sml[wofs] = (u32)rl | ((u32)il << 16);
    }
    __syncthreads();
    u16* slab = H + (size_t)blockIdx.y * SLOT_U16;
    uint4* gdst = half ? ((uint4*)slab + SLAB_U4) : (uint4*)slab;
    const u32* sm = half ? sml : smh;
    #pragma unroll
    for (int icb = 0; icb < 8; ++icb)
        #pragma unroll
        for (int q = 0; q < 2; ++q){
            uint4 v;
            #pragma unroll
            for (int d = 0; d < 4; ++d)
                ((u32*)&v)[d] = sm[pxl*64 + ((icb*8 + q*4 + d) ^ (pxl & 31))];
            gdst[((size_t)icb*SP + px)*2 + q] = v;
        }
}

// ---- i2h: 2-channel input conv + ALL biases -> pre (float2 [t][64][SP]) -------------------------
__global__ __launch_bounds__(256) void i2h_kernel(
    const float* __restrict__ in_r, const float* __restrict__ in_i,
    const float* __restrict__ w2r,  const float* __restrict__ w2i,
    const float* __restrict__ b2r,  const float* __restrict__ b2i,
    const float* __restrict__ bihr, const float* __restrict__ bihi,
    const float* __restrict__ bhhr, const float* __restrict__ bhhi,
    float2* __restrict__ pre)
{
    const int t = blockIdx.z, oc0 = blockIdx.y*8;
    const int px = blockIdx.x*256 + threadIdx.x;
    const int x = px/NXY, y = px - x*NXY;
    int offs[9];
    #pragma unroll
    for (int dx=-1; dx<=1; ++dx)
        #pragma unroll
        for (int dy=-1; dy<=1; ++dy)
            offs[(dx+1)*3+(dy+1)] = refl(x+dx)*NXY + refl(y+dy);
    float xr[2][9], xi[2][9];
    #pragma unroll
    for (int ic=0; ic<2; ++ic)
        #pragma unroll
        for (int k=0; k<9; ++k){
            xr[ic][k] = in_r[((size_t)ic*NT+t)*SP + offs[k]];
            xi[ic][k] = in_i[((size_t)ic*NT+t)*SP + offs[k]];
        }
    #pragma unroll
    for (int o=0; o<8; ++o){
        int oc = oc0+o;
        float ar = b2r[oc]+bihr[oc]+bhhr[oc];
        float ai = b2i[oc]+bihi[oc]+bhhi[oc];
        #pragma unroll
        for (int ic=0; ic<2; ++ic)
            #pragma unroll
            for (int k=0; k<9; ++k){
                float wr = w2r[(oc*2+ic)*9+k], wi = w2i[(oc*2+ic)*9+k];
                ar = fmaf(xr[ic][k], wr, ar); ar = fmaf(-xi[ic][k], wi, ar);
                ai = fmaf(xr[ic][k], wi, ai); ai = fmaf( xi[ic][k], wr, ai);
            }
        pre[((size_t)t*64+oc)*SP + px] = make_float2(ar, ai);
    }
}

// ---- GEMM: 32x32x16 MFMA, block = 4 waves (2M x 2N), 256 px, A per-half-tap LDS dbuf ------------
template<int MODE>
__global__ __launch_bounds__(256, 1) void gemm_kernel(
    const uint4* __restrict__ A4,      // [72][hl][MT][lane] uint4; phase ph at +ph*2048
    const u16* __restrict__ Hbase,     // B slab region
    float2* __restrict__ pre_b,        // MODE0: pre + t0*64*SP ; MODE1: pre
    float2* __restrict__ out,
    const float* __restrict__ modb,
    u16* __restrict__ Hw,
    int s)
{
    __shared__ uint4 lds[4096];        // 64KB: 2 x 32KB phase buffers
    const int tid = threadIdx.x;
    const int lane = tid & 63, w = tid >> 6;
    const int mgrp = w >> 1, ngrp = w & 1;
    const int l31 = lane & 31, kh = lane >> 5;

    const uint4* Bh4; float2* pre_t;
    int dir = 0, t = 0;
    if constexpr (MODE==0){
        Bh4 = (const uint4*)(Hbase + (size_t)blockIdx.y * SLOT_U16);
        pre_t = pre_b + (size_t)blockIdx.y * 64 * SP;
    } else {
        dir = blockIdx.y;
        int rp = (s+1) & 1;
        Bh4 = (const uint4*)(Hbase + (size_t)(dir*2+rp) * SLOT_U16);
        t = dir ? (NT-1-s) : s;
        pre_t = pre_b + (size_t)t * 64 * SP;
    }
    const uint4* Bl4 = Bh4 + SLAB_U4;

    const int px0 = blockIdx.x * 256;
    const int wbase = px0 + ngrp * 128;
    int xr[4], yc[4];
    #pragma unroll
    for (int nt = 0; nt < 4; ++nt){
        int px = wbase + nt*32 + l31;
        xr[nt] = px / NXY; yc[nt] = px - xr[nt]*NXY;
    }

    f32x16 acc[2][4];
    #pragma unroll
    for (int mt = 0; mt < 2; ++mt)
        #pragma unroll
        for (int nt = 0; nt < 4; ++nt) acc[mt][nt] = (f32x16)0.f;

    const bool hasK = (MODE==0) || (s > 0);
    if (hasK){
        auto stage = [&](int ph, int buf){
            const char* g = ((const char*)A4) + (size_t)ph*32768 + tid*16;
            char* l = ((char*)lds) + buf*32768 + tid*16;
            #pragma unroll
            for (int i = 0; i < 8; ++i)
                __builtin_amdgcn_global_load_lds(
                    (const __attribute__((address_space(1))) u32*)(g + i*4096),
                    (__attribute__((address_space(3))) u32*)(l + i*4096), 16, 0, 0);
        };
        auto loadB = [&](uint4 (&bh)[4], uint4 (&bl)[4], int icb, const int (&po)[4]){
            #pragma unroll
            for (int nt = 0; nt < 4; ++nt){
                size_t o = ((size_t)icb*SP + po[nt])*2 + kh;
                bh[nt] = Bh4[o]; bl[nt] = Bl4[o];
            }
        };
        auto subcomp = [&](int buf, int subl, const uint4 (&bh)[4], const uint4 (&bl)[4]){
            bf16x8 ah[2], al[2];
            #pragma unroll
            for (int mt = 0; mt < 2; ++mt){
                ah[mt] = as_bf(lds[buf*2048 + ((subl*2+0)*4 + mgrp*2+mt)*64 + lane]);
                al[mt] = as_bf(lds[buf*2048 + ((subl*2+1)*4 + mgrp*2+mt)*64 + lane]);
            }
            bf16x8 bhf[4], blf[4];
            #pragma unroll
            for (int nt = 0; nt < 4; ++nt){ bhf[nt] = as_bf(bh[nt]); blf[nt] = as_bf(bl[nt]); }
            #pragma unroll
            for (int mt = 0; mt < 2; ++mt)
                #pragma unroll
                for (int nt = 0; nt < 4; ++nt)
                    acc[mt][nt] = __builtin_amdgcn_mfma_f32_32x32x16_bf16(ah[mt], bhf[nt], acc[mt][nt], 0,0,0);
            #pragma unroll
            for (int mt = 0; mt < 2; ++mt)
                #pragma unroll
                for (int nt = 0; nt < 4; ++nt)
                    acc[mt][nt] = __builtin_amdgcn_mfma_f32_32x32x16_bf16(ah[mt], blf[nt], acc[mt][nt], 0,0,0);
            #pragma unroll
            for (int mt = 0; mt < 2; ++mt)
                #pragma unroll
                for (int nt = 0; nt < 4; ++nt)
                    acc[mt][nt] = __builtin_amdgcn_mfma_f32_32x32x16_bf16(al[mt], bhf[nt], acc[mt][nt], 0,0,0);
        };

        int poC[4], poN[4];
        uint4 bhA[4], blA[4], bhB[4], blB[4];
        {   // tap 0
            #pragma unroll
            for (int nt = 0; nt < 4; ++nt)
                poC[nt] = refl(xr[nt]-1)*NXY + refl(yc[nt]-1);
        }
        loadB(bhA, blA, 0, poC);
        loadB(bhB, blB, 1, poC);
        stage(0, 0);
        __syncthreads();

        for (int tap = 0; tap < 9; ++tap){
            {
                int dx = tap/3 - 1, dy = tap - (tap/3)*3 - 1;
                #pragma unroll
                for (int nt = 0; nt < 4; ++nt)
                    poC[nt] = refl(xr[nt]+dx)*NXY + refl(yc[nt]+dy);
                int tp1 = tap < 8 ? tap+1 : 8;
                int dx1 = tp1/3 - 1, dy1 = tp1 - (tp1/3)*3 - 1;
                #pragma unroll
                for (int nt = 0; nt < 4; ++nt)
                    poN[nt] = refl(xr[nt]+dx1)*NXY + refl(yc[nt]+dy1);
            }
            // ---- phase A (half 0): buf0, icbs 0-3
            stage(tap*2+1, 1);
            subcomp(0, 0, bhA, blA); loadB(bhA, blA, 2, poC);
            subcomp(0, 1, bhB, blB); loadB(bhB, blB, 3, poC);
            subcomp(0, 2, bhA, blA); loadB(bhA, blA, 4, poC);
            subcomp(0, 3, bhB, blB); loadB(bhB, blB, 5, poC);
            __syncthreads();
            // ---- phase B (half 1): buf1, icbs 4-7
            if (tap < 8) stage(tap*2+2, 0);
            subcomp(1, 0, bhA, blA); loadB(bhA, blA, 6, poC);
            subcomp(1, 1, bhB, blB); loadB(bhB, blB, 7, poC);
            subcomp(1, 2, bhA, blA); if (tap < 8) loadB(bhA, blA, 0, poN);
            subcomp(1, 3, bhB, blB); if (tap < 8) loadB(bhB, blB, 1, poN);
            __syncthreads();
        }
    }

    if constexpr (MODE==0){
        #pragma unroll
        for (int mt = 0; mt < 2; ++mt){
            const int MT = mgrp*2 + mt;
            #pragma unroll
            for (int nt = 0; nt < 4; ++nt){
                int px = wbase + nt*32 + l31;
                #pragma unroll
                for (int g = 0; g < 2; ++g)
                    #pragma unroll
                    for (int d = 0; d < 4; ++d){
                        int oc = MT*16 + g*8 + kh*4 + d;
                        float2 p = pre_t[(size_t)oc*SP + px];
                        p.x += acc[mt][nt][g*4+d];
                        p.y += acc[mt][nt][(g+2)*4+d];
                        pre_t[(size_t)oc*SP + px] = p;
                    }
            }
        }
    } else {
        u16* Chw = Hw + (size_t)(dir*2 + (s&1)) * SLOT_U16;
        uint4* Ch4 = (uint4*)Chw;
        uint4* Cl4 = Ch4 + SLAB_U4;
        const bool first = (s <= 5);
        #pragma unroll
        for (int mt = 0; mt < 2; ++mt){
            const int MT = mgrp*2 + mt;
            #pragma unroll
            for (int nt = 0; nt < 4; ++nt){
                int px = wbase + nt*32 + l31;
                #pragma unroll
                for (int g = 0; g < 2; ++g){
                    uint4 hv, lv;
                    #pragma unroll
                    for (int d = 0; d < 4; ++d){
                        int oc = MT*16 + g*8 + kh*4 + d;
                        float2 p = pre_t[(size_t)oc*SP + px];
                        float zr = p.x + acc[mt][nt][g*4+d];
                        float zi = p.y + acc[mt][nt][(g+2)*4+d];
                        float mag = sqrtf(zr*zr + zi*zi);
                        float sc = fmaxf(mag + modb[oc], 0.f) / (mag + 1e-8f);
                        float hr = sc*zr, hm = sc*zi;
                        size_t oidx = ((size_t)oc*NT + t)*SP + px;
                        if (first) out[oidx] = make_float2(hr, hm);
                        else { float2 o2 = out[oidx]; out[oidx] = make_float2(o2.x+hr, o2.y+hm); }
                        u16 rh = bf16_rn(hr), ih = bf16_rn(hm);
                        u16 rl = bf16_rn(hr - bf16_f(rh)), il = bf16_rn(hm - bf16_f(ih));
                        ((u32*)&hv)[d] = (u32)rh | ((u32)ih<<16);
                        ((u32*)&lv)[d] = (u32)rl | ((u32)il<<16);
                    }
                    int icb = MT*2 + g;
                    size_t q = ((size_t)icb*SP + px)*2 + kh;
                    Ch4[q] = hv; Cl4[q] = lv;
                }
            }
        }
    }
}

extern "C" void kernel_launch(void* const* d_in, const int* in_sizes, int n_in,
                              void* d_out, int out_size, void* d_ws, size_t ws_size,
                              hipStream_t stream)
{
    const float* in_r  = (const float*)d_in[0];
    const float* in_i  = (const float*)d_in[1];
    const float* it_r  = (const float*)d_in[2];
    const float* it_i  = (const float*)d_in[3];
    const float* w2_r  = (const float*)d_in[4];
    const float* w2_i  = (const float*)d_in[5];
    const float* b2_r  = (const float*)d_in[6];
    const float* b2_i  = (const float*)d_in[7];
    const float* whh_r = (const float*)d_in[8];
    const float* whh_i = (const float*)d_in[9];
    const float* bhh_r = (const float*)d_in[10];
    const float* bhh_i = (const float*)d_in[11];
    const float* wih_r = (const float*)d_in[12];
    const float* wih_i = (const float*)d_in[13];
    const float* bih_r = (const float*)d_in[14];
    const float* bih_i = (const float*)d_in[15];
    const float* mod_b = (const float*)d_in[16];

    char* ws = (char*)d_ws;
    float2* pre = (float2*)ws;                             // 157,286,400 B
    u16*    H   = (u16*)(ws + 157286400);                  //  52,428,800 B (4 slots)
    u16*    Ahh = (u16*)(ws + 157286400 + 52428800);       //     589,824 B
    u16*    Aih = H + 2*SLOT_U16;                          // overlaps slots 2,3 (dead in MODE0 phase)
    float2* out = (float2*)d_out;

    pack_w_kernel<<<72, 256, 0, stream>>>(whh_r, whh_i, Ahh);
    pack_w_kernel<<<72, 256, 0, stream>>>(wih_r, wih_i, Aih);
    i2h_kernel<<<dim3(100,8,12), 256, 0, stream>>>(in_r, in_i, w2_r, w2_i,
        b2_r, b2_i, bih_r, bih_i, bhh_r, bhh_i, pre);
    for (int t0 = 0; t0 < NT; t0 += 2){
        pack_iter_kernel<<<dim3(200,2), 256, 0, stream>>>(it_r, it_i, H, t0);
        gemm_kernel<0><<<dim3(100,2), 256, 0, stream>>>((const uint4*)Aih, H,
            pre + (size_t)t0*64*SP, nullptr, nullptr, nullptr, 0);
    }
    for (int s = 0; s < NT; ++s)
        gemm_kernel<1><<<dim3(100,2), 256, 0, stream>>>((const uint4*)Ahh, H,
            pre, out, mod_b, H, s);
}

// Round 6
// 1408.528 us; speedup vs baseline: 1.5594x; 1.2880x over previous
//
#include <hip/hip_runtime.h>

#define NXY 160
#define NT 12
#define SP 25600
#define SLAB_U16 3276800ull          // one hi or lo slab: 8*SP*16 u16
#define SLOT_U16 6553600ull          // hi+lo pair
#define SLAB_U4  409600              // SLAB_U16/8

typedef unsigned short u16;
typedef unsigned int u32;
typedef float f32x16 __attribute__((ext_vector_type(16)));
typedef __bf16 bf16x8 __attribute__((ext_vector_type(8)));

__device__ __forceinline__ int refl(int p){ return p<0 ? -p : (p>=NXY ? 2*(NXY-1)-p : p); }
__device__ __forceinline__ u16 bf16_rn(float x){
    u32 u = __float_as_uint(x);
    return (u16)((u + 0x7fffu + ((u>>16)&1u)) >> 16);
}
__device__ __forceinline__ float bf16_f(u16 h){ return __uint_as_float(((u32)h)<<16); }
__device__ __forceinline__ bf16x8 as_bf(uint4 v){ return __builtin_bit_cast(bf16x8, v); }
__device__ __forceinline__ void glds16(const void* g, void* l){
    __builtin_amdgcn_global_load_lds(
        (const __attribute__((address_space(1))) u32*)g,
        (__attribute__((address_space(3))) u32*)l, 16, 0, 0);
}

// ---- pack weights: chunk c = icb*9+tap (8192 B): [hl 2][MT 4][lane 64][8 u16] -------------------
// A-frag k = (lane>>5)*8 + j -> ic = icb*8 + (k>>1), ri = k&1
// M row = MT*32 + (lane&31): oc = MT*16 + (row&15); row>>4: 0=real-out, 1=imag-out
__global__ void pack_w_kernel(const float* __restrict__ wr, const float* __restrict__ wi,
                              u16* __restrict__ Ap)
{
    const int c = blockIdx.x;                 // 0..71
    const int icb = c/9, tap = c - icb*9;
    const int t = threadIdx.x;
    const int lane = t & 63, MT = t >> 6;
    const int row = lane & 31;
    const int oc = MT*16 + (row & 15);
    const int ri_out = row >> 4;
    const int kh = lane >> 5;
    #pragma unroll
    for (int j = 0; j < 8; ++j){
        int ic = icb*8 + kh*4 + (j>>1);
        int ri = j & 1;
        float wrv = wr[(oc*64+ic)*9 + tap];
        float wiv = wi[(oc*64+ic)*9 + tap];
        float val = (ri_out==0) ? (ri ? -wiv : wrv) : (ri ? wrv : wiv);
        u16 h = bf16_rn(val);
        Ap[(size_t)c*4096 + ((0*4 + MT)*64 + lane)*8 + j] = h;
        Ap[(size_t)c*4096 + ((1*4 + MT)*64 + lane)*8 + j] = bf16_rn(val - bf16_f(h));
    }
}

// ---- pack iter into B-slab layout: [icb 8][px][2 uint4] hi-slab + lo-slab, 2 t per launch -------
__global__ __launch_bounds__(256) void pack_iter_kernel(const float* __restrict__ it_r,
        const float* __restrict__ it_i, u16* __restrict__ H, int t0)
{
    __shared__ u32 smh[8192], sml[8192];
    const int t = t0 + blockIdx.y;
    const int tid = threadIdx.x;
    const int pxl = tid & 127, half = tid >> 7;
    const int px0 = blockIdx.x * 128;
    const int px = px0 + pxl;
    #pragma unroll 4
    for (int i = 0; i < 32; ++i){
        int ic = half*32 + i;
        float r  = it_r[((size_t)ic*NT + t)*SP + px];
        float im = it_i[((size_t)ic*NT + t)*SP + px];
        u16 rh = bf16_rn(r),  ih = bf16_rn(im);
        u16 rl = bf16_rn(r - bf16_f(rh)), il = bf16_rn(im - bf16_f(ih));
        int wofs = pxl*64 + (ic ^ (pxl & 31));
        smh[wofs] = (u32)rh | ((u32)ih << 16);
        sml[wofs] = (u32)rl | ((u32)il << 16);
    }
    __syncthreads();
    u16* slab = H + (size_t)blockIdx.y * SLOT_U16;
    uint4* gdst = half ? ((uint4*)slab + SLAB_U4) : (uint4*)slab;
    const u32* sm = half ? sml : smh;
    #pragma unroll
    for (int icb = 0; icb < 8; ++icb)
        #pragma unroll
        for (int q = 0; q < 2; ++q){
            uint4 v;
            #pragma unroll
            for (int d = 0; d < 4; ++d)
                ((u32*)&v)[d] = sm[pxl*64 + ((icb*8 + q*4 + d) ^ (pxl & 31))];
            gdst[((size_t)icb*SP + px)*2 + q] = v;
        }
}

// ---- i2h: 2-channel input conv + ALL biases -> pre (float2 [t][64][SP]) -------------------------
__global__ __launch_bounds__(256) void i2h_kernel(
    const float* __restrict__ in_r, const float* __restrict__ in_i,
    const float* __restrict__ w2r,  const float* __restrict__ w2i,
    const float* __restrict__ b2r,  const float* __restrict__ b2i,
    const float* __restrict__ bihr, const float* __restrict__ bihi,
    const float* __restrict__ bhhr, const float* __restrict__ bhhi,
    float2* __restrict__ pre)
{
    const int t = blockIdx.z, oc0 = blockIdx.y*8;
    const int px = blockIdx.x*256 + threadIdx.x;
    const int x = px/NXY, y = px - x*NXY;
    int offs[9];
    #pragma unroll
    for (int dx=-1; dx<=1; ++dx)
        #pragma unroll
        for (int dy=-1; dy<=1; ++dy)
            offs[(dx+1)*3+(dy+1)] = refl(x+dx)*NXY + refl(y+dy);
    float xr[2][9], xi[2][9];
    #pragma unroll
    for (int ic=0; ic<2; ++ic)
        #pragma unroll
        for (int k=0; k<9; ++k){
            xr[ic][k] = in_r[((size_t)ic*NT+t)*SP + offs[k]];
            xi[ic][k] = in_i[((size_t)ic*NT+t)*SP + offs[k]];
        }
    #pragma unroll
    for (int o=0; o<8; ++o){
        int oc = oc0+o;
        float ar = b2r[oc]+bihr[oc]+bhhr[oc];
        float ai = b2i[oc]+bihi[oc]+bhhi[oc];
        #pragma unroll
        for (int ic=0; ic<2; ++ic)
            #pragma unroll
            for (int k=0; k<9; ++k){
                float wr = w2r[(oc*2+ic)*9+k], wi = w2i[(oc*2+ic)*9+k];
                ar = fmaf(xr[ic][k], wr, ar); ar = fmaf(-xi[ic][k], wi, ar);
                ai = fmaf(xr[ic][k], wi, ai); ai = fmaf( xi[ic][k], wr, ai);
            }
        pre[((size_t)t*64+oc)*SP + px] = make_float2(ar, ai);
    }
}

// ---- GEMM: 32x32x16, block = 4 waves (2M x 2N), 8x16-px tile, B halo in LDS, 72-phase pipeline --
template<int MODE>
__global__ __launch_bounds__(256, 2) void gemm_kernel(
    const uint4* __restrict__ A4,      // [72 chunks][hl][4 MT][64 lane] uint4
    const u16* __restrict__ Hbase,
    float2* __restrict__ pre_b,
    float2* __restrict__ out,
    const float* __restrict__ modb,
    u16* __restrict__ Hw,
    int s)
{
    __shared__ uint4 ldsA[1536];       // 3 x 8KB A chunk buffers
    __shared__ uint4 ldsB[1536];       // 2 x 12KB B halo buffers (720 used + pad)
    const int tid = threadIdx.x;
    const int lane = tid & 63, w = tid >> 6;
    const int mgrp = w >> 1, ngrp = w & 1;
    const int l31 = lane & 31, kh = lane >> 5;
    const int tile = blockIdx.x;
    const int x0 = (tile/10)*8, y0 = (tile - (tile/10)*10)*16;

    const uint4* Bh4; float2* pre_t;
    int dir = 0, t = 0;
    if constexpr (MODE==0){
        Bh4 = (const uint4*)(Hbase + (size_t)blockIdx.y * SLOT_U16);
        pre_t = pre_b + (size_t)blockIdx.y * 64 * SP;
    } else {
        dir = blockIdx.y;
        int rp = (s+1) & 1;
        Bh4 = (const uint4*)(Hbase + (size_t)(dir*2+rp) * SLOT_U16);
        t = dir ? (NT-1-s) : s;
        pre_t = pre_b + (size_t)t * 64 * SP;
    }

    f32x16 acc[2][2];
    #pragma unroll
    for (int mt=0; mt<2; ++mt)
        #pragma unroll
        for (int nt=0; nt<2; ++nt) acc[mt][nt] = (f32x16)0.f;

    const bool hasK = (MODE==0) || (s > 0);
    if (hasK){
        const int rowp = ngrp*4 + (l31>>4) + 1;   // halo row base (before nt*2, dx)
        const int colp = (l31&15) + 1;            // halo col base (before dy)

        auto stageA = [&](int c, int buf){
            const char* g = ((const char*)A4) + (size_t)c*8192 + tid*16;
            char* l = ((char*)ldsA) + buf*8192 + tid*16;
            glds16(g, l); glds16(g + 4096, l + 4096);
        };
        auto stageB = [&](int icb, int buf){
            #pragma unroll
            for (int i = 0; i < 3; ++i){
                int e = i*256 + tid;
                int ew = e >= 720 ? e - 720 : e;
                int hl = ew >= 360;
                int e3 = ew - hl*360;
                int hx = e3/36, r2 = e3 - hx*36;
                int hy = r2 >> 1, qslot = r2 & 1;
                int qs = qslot ^ ((hy>>2)&1);
                int gx = refl(x0-1+hx), gy = refl(y0-1+hy);
                const uint4* src = Bh4 + (size_t)hl*SLAB_U4 + ((size_t)icb*SP + gx*NXY+gy)*2 + qs;
                glds16(src, ((char*)ldsB) + buf*12288 + e*16);
            }
        };

        struct Frags { bf16x8 ah[2], al[2], bh[2], bl[2]; };
        auto readF = [&](Frags& f, int abuf, int bbuf, int dx, int dy){
            #pragma unroll
            for (int mt=0; mt<2; ++mt){
                f.ah[mt] = as_bf(ldsA[abuf*512 +       (mgrp*2+mt)*64 + lane]);
                f.al[mt] = as_bf(ldsA[abuf*512 + 256 + (mgrp*2+mt)*64 + lane]);
            }
            const int hy = colp + dy;
            const int qx = kh ^ ((hy>>2)&1);
            #pragma unroll
            for (int nt=0; nt<2; ++nt){
                int base = bbuf*768 + (rowp + nt*2 + dx)*36 + hy*2 + qx;
                f.bh[nt] = as_bf(ldsB[base]);
                f.bl[nt] = as_bf(ldsB[base + 360]);
            }
        };
        auto mfma12 = [&](const Frags& f){
            #pragma unroll
            for (int mt=0; mt<2; ++mt)
                #pragma unroll
                for (int nt=0; nt<2; ++nt){
                    acc[mt][nt] = __builtin_amdgcn_mfma_f32_32x32x16_bf16(f.ah[mt], f.bh[nt], acc[mt][nt], 0,0,0);
                    acc[mt][nt] = __builtin_amdgcn_mfma_f32_32x32x16_bf16(f.ah[mt], f.bl[nt], acc[mt][nt], 0,0,0);
                    acc[mt][nt] = __builtin_amdgcn_mfma_f32_32x32x16_bf16(f.al[mt], f.bh[nt], acc[mt][nt], 0,0,0);
                }
        };

        Frags f0, f1, f2;
        // prologue: A chunks 0,1 and B(icb=0); drain; read frags for phase 0
        stageA(0, 0); stageA(1, 1); stageB(0, 0);
        __syncthreads();
        readF(f0, 0, 0, -1, -1);

#define DO_PHASE(TAP, FC, FN, SB, ABN, DXN, DYN, LAST)                        \
        {                                                                      \
            if (icb*9 + TAP + 2 < 72) stageA(icb*9 + TAP + 2, SB);             \
            if (TAP == 0 && icb < 7) stageB(icb+1, bb^1);                      \
            if (!LAST) readF(FN, ABN, bb, DXN, DYN);                           \
            else if (icb < 7) readF(FN, ABN, bb^1, DXN, DYN);                  \
            __builtin_amdgcn_s_setprio(1);                                     \
            mfma12(FC);                                                        \
            __builtin_amdgcn_s_setprio(0);                                     \
            __syncthreads();                                                   \
        }

        for (int icb = 0; icb < 8; ++icb){
            const int bb = icb & 1;
            DO_PHASE(0, f0, f1, 2, 1, -1,  0, false)
            DO_PHASE(1, f1, f2, 0, 2, -1,  1, false)
            DO_PHASE(2, f2, f0, 1, 0,  0, -1, false)
            DO_PHASE(3, f0, f1, 2, 1,  0,  0, false)
            DO_PHASE(4, f1, f2, 0, 2,  0,  1, false)
            DO_PHASE(5, f2, f0, 1, 0,  1, -1, false)
            DO_PHASE(6, f0, f1, 2, 1,  1,  0, false)
            DO_PHASE(7, f1, f2, 0, 2,  1,  1, false)
            DO_PHASE(8, f2, f0, 1, 0, -1, -1, true)
        }
#undef DO_PHASE
    }

    if constexpr (MODE==0){
        #pragma unroll
        for (int mt=0; mt<2; ++mt){
            const int MT = mgrp*2 + mt;
            #pragma unroll
            for (int nt=0; nt<2; ++nt){
                const int row = ngrp*4 + nt*2 + (l31>>4);
                const int px = (x0+row)*NXY + y0 + (l31&15);
                #pragma unroll
                for (int g=0; g<2; ++g)
                    #pragma unroll
                    for (int d=0; d<4; ++d){
                        int oc = MT*16 + kh*4 + d + 8*g;
                        float2 p = pre_t[(size_t)oc*SP + px];
                        p.x += acc[mt][nt][g*4+d];
                        p.y += acc[mt][nt][g*4+d+8];
                        pre_t[(size_t)oc*SP + px] = p;
                    }
            }
        }
    } else {
        u16* Chw = Hw + (size_t)(dir*2 + (s&1)) * SLOT_U16;
        uint4* Ch4w = (uint4*)Chw;
        uint4* Cl4w = Ch4w + SLAB_U4;
        const bool first = (s <= 5);
        #pragma unroll
        for (int mt=0; mt<2; ++mt){
            const int MT = mgrp*2 + mt;
            #pragma unroll
            for (int nt=0; nt<2; ++nt){
                const int row = ngrp*4 + nt*2 + (l31>>4);
                const int px = (x0+row)*NXY + y0 + (l31&15);
                #pragma unroll
                for (int g=0; g<2; ++g){
                    uint4 hv, lv;
                    #pragma unroll
                    for (int d=0; d<4; ++d){
                        int oc = MT*16 + kh*4 + d + 8*g;
                        float2 p = pre_t[(size_t)oc*SP + px];
                        float zr = p.x + acc[mt][nt][g*4+d];
                        float zi = p.y + acc[mt][nt][g*4+d+8];
                        float mag = sqrtf(zr*zr + zi*zi);
                        float sc = fmaxf(mag + modb[oc], 0.f) / (mag + 1e-8f);
                        float hr = sc*zr, hm = sc*zi;
                        size_t oidx = ((size_t)oc*NT + t)*SP + px;
                        if (first) out[oidx] = make_float2(hr, hm);
                        else { float2 o2 = out[oidx]; out[oidx] = make_float2(o2.x+hr, o2.y+hm); }
                        u16 rh = bf16_rn(hr), ih = bf16_rn(hm);
                        u16 rl = bf16_rn(hr - bf16_f(rh)), il = bf16_rn(hm - bf16_f(ih));
                        ((u32*)&hv)[d] = (u32)rh | ((u32)ih<<16);
                        ((u32*)&lv)[d] = (u32)rl | ((u32)il<<16);
                    }
                    int icbh = MT*2 + g;
                    size_t q = ((size_t)icbh*SP + px)*2 + kh;
                    Ch4w[q] = hv; Cl4w[q] = lv;
                }
            }
        }
    }
}

extern "C" void kernel_launch(void* const* d_in, const int* in_sizes, int n_in,
                              void* d_out, int out_size, void* d_ws, size_t ws_size,
                              hipStream_t stream)
{
    const float* in_r  = (const float*)d_in[0];
    const float* in_i  = (const float*)d_in[1];
    const float* it_r  = (const float*)d_in[2];
    const float* it_i  = (const float*)d_in[3];
    const float* w2_r  = (const float*)d_in[4];
    const float* w2_i  = (const float*)d_in[5];
    const float* b2_r  = (const float*)d_in[6];
    const float* b2_i  = (const float*)d_in[7];
    const float* whh_r = (const float*)d_in[8];
    const float* whh_i = (const float*)d_in[9];
    const float* bhh_r = (const float*)d_in[10];
    const float* bhh_i = (const float*)d_in[11];
    const float* wih_r = (const float*)d_in[12];
    const float* wih_i = (const float*)d_in[13];
    const float* bih_r = (const float*)d_in[14];
    const float* bih_i = (const float*)d_in[15];
    const float* mod_b = (const float*)d_in[16];

    char* ws = (char*)d_ws;
    float2* pre = (float2*)ws;                             // 157,286,400 B
    u16*    H   = (u16*)(ws + 157286400);                  //  52,428,800 B (4 slots)
    u16*    Ahh = (u16*)(ws + 157286400 + 52428800);       //     589,824 B
    u16*    Aih = H + 2*SLOT_U16;                          // overlaps slots 2,3 (dead in MODE0 phase)
    float2* out = (float2*)d_out;

    pack_w_kernel<<<72, 256, 0, stream>>>(whh_r, whh_i, Ahh);
    pack_w_kernel<<<72, 256, 0, stream>>>(wih_r, wih_i, Aih);
    i2h_kernel<<<dim3(100,8,12), 256, 0, stream>>>(in_r, in_i, w2_r, w2_i,
        b2_r, b2_i, bih_r, bih_i, bhh_r, bhh_i, pre);
    for (int t0 = 0; t0 < NT; t0 += 2){
        pack_iter_kernel<<<dim3(200,2), 256, 0, stream>>>(it_r, it_i, H, t0);
        gemm_kernel<0><<<dim3(200,2), 256, 0, stream>>>((const uint4*)Aih, H,
            pre + (size_t)t0*64*SP, nullptr, nullptr, nullptr, 0);
    }
    for (int s = 0; s < NT; ++s)
        gemm_kernel<1><<<dim3(200,2), 256, 0, stream>>>((const uint4*)Ahh, H,
            pre, out, mod_b, H, s);
}